// Round 8
// baseline (786.195 us; speedup 1.0000x reference)
//
#include <hip/hip_runtime.h>
#include <hip/hip_bf16.h>

// x: (4, 256, 32, 32, 32) fp32; qkv_weight: (512, 256); relative: (64, 63);
// gamma/beta: (512,). Output: (4, 256, 32, 32, 32) fp32.
//
// K0b: transpose+split x fp32 [k][sp] -> xThi/xTlo bf16 [sp][k] (hi + residual).
//      Lives in the stk2 region (dead until K2 writes it).
// K1:  MFMA GEMM qkv = W @ x, 3-term bf16 split (fp32-equivalent precision).
//      BARRIER-FREE, NO LDS: B-frags are single 16B loads from xT (k-contiguous);
//      W loaded fp32 (L2-resident) and split in-register. otile in HIGH bits of
//      bx so the 4 blocks sharing an xT strip land on the SAME XCD (siblings
//      differ by 256 = 0 mod 8). Output in Q2 layout:
//      Q2[b][w][head][tc][ch][i][tt]  (chunk-major per (b,w,head) block).
// K2:  MFMA attention per (b,head,w); staging reads Q2 fully coalesced.
// K3:  BN finalize + pair-sum, LDS transpose batched 4 i-rows/barrier.

typedef __attribute__((ext_vector_type(8))) short short8;
typedef __attribute__((ext_vector_type(16))) float f32x16;

__device__ inline unsigned short f2bu(float f) {
  __hip_bfloat16 h = __float2bfloat16(f);
  return *(unsigned short*)&h;
}

#define MFMA32(A, B, C) __builtin_amdgcn_mfma_f32_32x32x16_bf16(A, B, C, 0, 0, 0)

// K2 slab padding: [i][ch][tt]  addr = i*S_I + ch*S_C + tt
constexpr int S_I = 646;
constexpr int S_C = 10;

// ---------------- K0b: x transpose + split fp32 -> bf16 hi/lo, [sp][k] ----------------
__global__ __launch_bounds__(256) void k0_xsplit(
    const float* __restrict__ x, unsigned short* __restrict__ xThi,
    unsigned short* __restrict__ xTlo) {
  // grid 2048 = b(4) x ktile(4) x sptile(128); block covers 256 sp x 64 k.
  const int bx = blockIdx.x;
  const int spt = bx & 127, kt = (bx >> 7) & 3, b = bx >> 9;
  const int sp = spt * 256 + threadIdx.x;
  const int k0 = kt * 64;
  const float* xs = x + (size_t)b * 8388608 + (size_t)k0 * 32768 + sp;
  unsigned int hiw[32], low[32];
#pragma unroll
  for (int m = 0; m < 32; ++m) {
    const float f0 = xs[(size_t)(2 * m) * 32768];
    const float f1 = xs[(size_t)(2 * m + 1) * 32768];
    const unsigned u0 = __float_as_uint(f0), u1 = __float_as_uint(f1);
    const float l0 = f0 - __uint_as_float(u0 & 0xFFFF0000u);
    const float l1 = f1 - __uint_as_float(u1 & 0xFFFF0000u);
    hiw[m] = (u0 >> 16) | ((u1 >> 16) << 16);
    low[m] = (__float_as_uint(l0) >> 16) | ((__float_as_uint(l1) >> 16) << 16);
  }
  unsigned short* dh = xThi + (size_t)b * 8388608 + (size_t)sp * 256 + k0;
  unsigned short* dl = xTlo + (size_t)b * 8388608 + (size_t)sp * 256 + k0;
#pragma unroll
  for (int q = 0; q < 8; ++q) {
    uint4 vh, vl;
    vh.x = hiw[4 * q]; vh.y = hiw[4 * q + 1]; vh.z = hiw[4 * q + 2]; vh.w = hiw[4 * q + 3];
    vl.x = low[4 * q]; vl.y = low[4 * q + 1]; vl.z = low[4 * q + 2]; vl.w = low[4 * q + 3];
    *(uint4*)(dh + 8 * q) = vh;
    *(uint4*)(dl + 8 * q) = vl;
  }
}

// ---------------- K1: MFMA QKV GEMM (barrier-free, no LDS) ----------------
__global__ __launch_bounds__(256) void k1_mfma(
    const float* __restrict__ Wq, const unsigned short* __restrict__ xThi,
    const unsigned short* __restrict__ xTlo, __hip_bfloat16* __restrict__ qkv) {
  const int td = threadIdx.x, bx = blockIdx.x;
  // otile HIGH bits: siblings (same b,nt; otile 0..3) differ by 256 == 0 mod 8
  // -> same XCD -> xT strip served by that XCD's L2.
  const int nt = bx & 255, otile = (bx >> 8) & 3, b = bx >> 10;
  const int w = nt & 31, i0 = (nt >> 5) << 2;  // 4 consecutive i-rows
  const int o0 = otile * 128;

  const int wid = td >> 6, l = td & 63, h = l >> 5, n = l & 31;
  const int wo = wid >> 1, wn = wid & 1;  // 2x2 waves over (o, c), 64x64 each

  // Column c = wn*64 + jt*32 + n  ->  spatial (i0+(n>>3))*1024 + w*32 + (wn*2+jt)*8 + (n&7)
  const int sp0 = (i0 + (n >> 3)) * 1024 + w * 32 + (wn * 2) * 8 + (n & 7);
  const unsigned short* pxh = xThi + (size_t)b * 8388608 + (size_t)sp0 * 256 + h * 8;
  const unsigned short* pxl = xTlo + (size_t)b * 8388608 + (size_t)sp0 * 256 + h * 8;
  // jt=1 -> sp += 8 -> +8*256 = +2048 elems
  const float* pw = Wq + (size_t)(o0 + wo * 64 + n) * 256 + h * 8;  // it=1: +32*256

  const f32x16 zf = {0, 0, 0, 0, 0, 0, 0, 0, 0, 0, 0, 0, 0, 0, 0, 0};
  f32x16 acc00 = zf, acc01 = zf, acc10 = zf, acc11 = zf;

#pragma unroll 2
  for (int kf = 0; kf < 16; ++kf) {  // kbase = kf*16 + h*8 (same order as before)
    const int kb = kf * 16;
    // B-frags: single 16B loads, k-contiguous
    const short8 bhi0 = *(const short8*)(pxh + kb);
    const short8 blo0 = *(const short8*)(pxl + kb);
    const short8 bhi1 = *(const short8*)(pxh + 2048 + kb);
    const short8 blo1 = *(const short8*)(pxl + 2048 + kb);
    // W fp32 (L2-resident), split in-register
    const float4 w0a = *(const float4*)(pw + kb);
    const float4 w0b = *(const float4*)(pw + kb + 4);
    const float4 w1a = *(const float4*)(pw + 32 * 256 + kb);
    const float4 w1b = *(const float4*)(pw + 32 * 256 + kb + 4);
    float wv0[8] = {w0a.x, w0a.y, w0a.z, w0a.w, w0b.x, w0b.y, w0b.z, w0b.w};
    float wv1[8] = {w1a.x, w1a.y, w1a.z, w1a.w, w1b.x, w1b.y, w1b.z, w1b.w};
    short8 ahi0, alo0, ahi1, alo1;
#pragma unroll
    for (int e = 0; e < 8; ++e) {
      const unsigned u0 = __float_as_uint(wv0[e]);
      ahi0[e] = (short)(u0 >> 16);
      alo0[e] = (short)(__float_as_uint(wv0[e] - __uint_as_float(u0 & 0xFFFF0000u)) >> 16);
      const unsigned u1 = __float_as_uint(wv1[e]);
      ahi1[e] = (short)(u1 >> 16);
      alo1[e] = (short)(__float_as_uint(wv1[e] - __uint_as_float(u1 & 0xFFFF0000u)) >> 16);
    }
    // 12 MFMAs, identical order to previous rounds (it outer, jt inner)
    acc00 = MFMA32(ahi0, bhi0, acc00);
    acc00 = MFMA32(ahi0, blo0, acc00);
    acc00 = MFMA32(alo0, bhi0, acc00);
    acc01 = MFMA32(ahi0, bhi1, acc01);
    acc01 = MFMA32(ahi0, blo1, acc01);
    acc01 = MFMA32(alo0, bhi1, acc01);
    acc10 = MFMA32(ahi1, bhi0, acc10);
    acc10 = MFMA32(ahi1, blo0, acc10);
    acc10 = MFMA32(alo1, bhi0, acc10);
    acc11 = MFMA32(ahi1, bhi1, acc11);
    acc11 = MFMA32(ahi1, blo1, acc11);
    acc11 = MFMA32(alo1, bhi1, acc11);
  }

  // Epilogue into Q2: addr = ((b*32+w)*8 + head)*65536 + tc*16384 + ch*256 + i0*8 + n
  // head = otile*2 + wo; tc = wn*2 + jt; ch = it*32 + (r&3)+8*(r>>2)+4*h.
  // 32 lanes (consecutive n) -> one full 64B line.
  __hip_bfloat16* qb2 = qkv + ((size_t)((b * 32 + w) * 8 + otile * 2 + wo)) * 65536 +
                        (size_t)(wn * 2) * 16384 + i0 * 8;
  const f32x16* accs[2][2] = {{&acc00, &acc01}, {&acc10, &acc11}};
#pragma unroll
  for (int jt = 0; jt < 2; ++jt) {
    __hip_bfloat16* bjt = qb2 + jt * 16384;
#pragma unroll
    for (int it = 0; it < 2; ++it) {
      const f32x16 a = *accs[it][jt];
#pragma unroll
      for (int r = 0; r < 16; ++r) {
        const int ch = it * 32 + (r & 3) + 8 * (r >> 2) + 4 * h;
        bjt[ch * 256 + n] = __float2bfloat16(a[r]);
      }
    }
  }
}

// ---------------- K2: MFMA attention (coalesced Q2 staging) ----------------
__global__ __launch_bounds__(256, 3) void k2_attn_mfma(
    const __hip_bfloat16* __restrict__ qkv, const float* __restrict__ rel,
    unsigned int* __restrict__ stk2, float* __restrict__ stats) {
  __shared__ __align__(16) __hip_bfloat16 slab[20672];      // [i][ch][tt] padded
  __shared__ __align__(16) unsigned short Sbuf[4 * 1280];   // per-wave sim [32][40] bf16
  __shared__ float statb[4][32][4];

  const int bx = blockIdx.x;
  const int w = bx & 31, head = (bx >> 5) & 7, b = bx >> 8;
  const int td = threadIdx.x;
  const int wid = td >> 6, l = td & 63, h = l >> 5, n = l & 31;

  short8 eqf[2], ekf[2], evf[4];
#pragma unroll
  for (int dt = 0; dt < 2; ++dt)
#pragma unroll
    for (int e = 0; e < 8; ++e) {
      int c = h * 8 + e, d = dt * 32 + n;
      eqf[dt][e] = (d < 63) ? (short)f2bu(rel[c * 63 + d]) : (short)0;
      ekf[dt][e] = (d < 63) ? (short)f2bu(rel[(16 + c) * 63 + d]) : (short)0;
    }
#pragma unroll
  for (int kh = 0; kh < 4; ++kh)
#pragma unroll
    for (int e = 0; e < 8; ++e) {
      int d = kh * 16 + h * 8 + e;
      evf[kh][e] = (d < 63) ? (short)f2bu(rel[(32 + n) * 63 + d]) : (short)0;
    }
  short8 ones;
#pragma unroll
  for (int e = 0; e < 8; ++e) ones[e] = (short)0x3F80;  // bf16 1.0

  // Q2 layout: block's data is 128 KB contiguous at ((b*32+w)*8+head)*65536
  const __hip_bfloat16* qbase = qkv + ((size_t)((b * 32 + w) * 8 + head)) * 65536;
  unsigned int* sb = stk2 + ((size_t)((b * 8 + head) * 32 + w)) * 32768;
  unsigned short* Sb = Sbuf + wid * 1280;

  const f32x16 zf = {0, 0, 0, 0, 0, 0, 0, 0, 0, 0, 0, 0, 0, 0, 0, 0};
  float st0 = 0, st1 = 0, st2 = 0, st3 = 0;

  for (int tc = 0; tc < 4; ++tc) {
    const int t0 = tc * 8;
    __syncthreads();  // previous chunk's readers done
    for (int r = 0; r < 8; ++r) {
      int idx = td + 256 * r;  // ch = idx>>5, i = idx&31
      const uint4 dat = *(const uint4*)(qbase + (size_t)tc * 16384 + (size_t)idx * 8);
      unsigned int* lp = (unsigned int*)(slab + (idx & 31) * S_I + (idx >> 5) * S_C);
      lp[0] = dat.x; lp[1] = dat.y; lp[2] = dat.z; lp[3] = dat.w;
    }
    __syncthreads();
    for (int u = 0; u < 2; ++u) {
      const int tt = 2 * wid + u;
      const int t = t0 + tt;
      short8 aq, ak;
#pragma unroll
      for (int e = 0; e < 8; ++e) {
        aq[e] = *(const short*)&slab[n * S_I + (h * 8 + e) * S_C + tt];
        ak[e] = *(const short*)&slab[n * S_I + (16 + h * 8 + e) * S_C + tt];
      }
      f32x16 qkD = MFMA32(aq, ak, zf);
      f32x16 Rq0 = MFMA32(aq, eqf[0], zf);
      f32x16 Rq1 = MFMA32(aq, eqf[1], zf);
      f32x16 Rk0 = MFMA32(ak, ekf[0], zf);
      f32x16 Rk1 = MFMA32(ak, ekf[1], zf);
#pragma unroll
      for (int r = 0; r < 16; ++r) {
        int rowr = (r & 3) + 8 * (r >> 2) + 4 * h;
        int d = rowr + n;
        int src = (d & 31) + 32 * h;
        float vq0 = __shfl(Rq0[r], src);
        float vq1 = __shfl(Rq1[r], src);
        float vk0 = __shfl(Rk0[r], src);
        float vk1 = __shfl(Rk1[r], src);
        float s = qkD[r] + (d < 32 ? vq0 + vk0 : vq1 + vk1);
        Sb[rowr * 40 + n] = f2bu(__expf(s));
      }
      short8 bv0, bv1;
#pragma unroll
      for (int e = 0; e < 8; ++e) {
        int j0 = h * 8 + e, j1 = 16 + h * 8 + e;
        bv0[e] = *(const short*)&slab[j0 * S_I + (32 + n) * S_C + tt];
        bv1[e] = *(const short*)&slab[j1 * S_I + (32 + n) * S_C + tt];
      }
      short8 as0 = *(const short8*)(Sb + n * 40 + h * 8);
      short8 as1 = *(const short8*)(Sb + n * 40 + 16 + h * 8);
      f32x16 svD = MFMA32(as1, bv1, MFMA32(as0, bv0, zf));
      f32x16 sumD = MFMA32(as1, ones, MFMA32(as0, ones, zf));
      f32x16 sveD = zf;
#pragma unroll
      for (int kh = 0; kh < 4; ++kh) {
        short8 ap;
#pragma unroll
        for (int e = 0; e < 8; ++e) {
          int k = kh * 16 + h * 8 + e;
          int jj = k - n;
          unsigned short raw = Sb[n * 40 + (jj & 31)];
          ap[e] = ((unsigned)jj < 32u) ? (short)raw : (short)0;
        }
        sveD = MFMA32(ap, evf[kh], sveD);
      }
#pragma unroll
      for (int r = 0; r < 16; ++r) {
        int rowr = (r & 3) + 8 * (r >> 2) + 4 * h;
        float inv = 1.0f / sumD[r];
        float svn = svD[r] * inv, sven = sveD[r] * inv;
        st0 += svn; st1 += svn * svn; st2 += sven; st3 += sven * sven;
        unsigned int pk = (unsigned int)f2bu(svn) | ((unsigned int)f2bu(sven) << 16);
        sb[((size_t)rowr * 32 + t) * 32 + n] = pk;
      }
    }
  }
  st0 += __shfl_xor(st0, 32); st1 += __shfl_xor(st1, 32);
  st2 += __shfl_xor(st2, 32); st3 += __shfl_xor(st3, 32);
  if (h == 0) {
    statb[wid][n][0] = st0; statb[wid][n][1] = st1;
    statb[wid][n][2] = st2; statb[wid][n][3] = st3;
  }
  __syncthreads();
  if (td < 32) {
    float a0 = 0, a1 = 0, a2 = 0, a3 = 0;
    for (int wv = 0; wv < 4; ++wv) {
      a0 += statb[wv][td][0]; a1 += statb[wv][td][1];
      a2 += statb[wv][td][2]; a3 += statb[wv][td][3];
    }
    const int o2 = head * 64 + 2 * td;
    atomicAdd(&stats[o2], a0);
    atomicAdd(&stats[o2 + 1], a2);
    atomicAdd(&stats[512 + o2], a1);
    atomicAdd(&stats[512 + o2 + 1], a3);
  }
}

// ---------------- K3: BN finalize + pair-sum, 4-row-batched LDS transpose ----------------
__global__ __launch_bounds__(256) void k3_finalize2(
    const unsigned int* __restrict__ stk2, const float* __restrict__ stats,
    const float* __restrict__ gamma, const float* __restrict__ beta,
    float* __restrict__ out) {
  __shared__ float trans[4][32][33];
  __shared__ float s_sc[64], s_sh[64];
  const int bx = blockIdx.x;
  const int w = bx & 31, head = (bx >> 5) & 7, b = bx >> 8;
  const int td = threadIdx.x;
  if (td < 64) {
    const int o2 = head * 64 + td;
    const float NINV = 1.f / 131072.f;
    float m = stats[o2] * NINV;
    float v = stats[512 + o2] * NINV - m * m;
    float sc = gamma[o2] * rsqrtf(v + 1e-5f);
    s_sc[td] = sc;
    s_sh[td] = beta[o2] - m * sc;
  }
  __syncthreads();
  const unsigned int* pb = stk2 + ((size_t)((b * 8 + head) * 32 + w)) * 32768;
  float* ob = out + ((size_t)(b * 256 + head * 32)) * 32768 + w * 32;
  const int t = td >> 3, c0 = (td & 7) * 4;
  const int t2 = td & 31, cbase = td >> 5;
  for (int i4 = 0; i4 < 32; i4 += 4) {
#pragma unroll
    for (int m = 0; m < 4; ++m) {
      const uint4 dat = *(const uint4*)(pb + (size_t)(i4 + m) * 1024 + td * 4);
      unsigned int dws[4] = {dat.x, dat.y, dat.z, dat.w};
#pragma unroll
      for (int q = 0; q < 4; ++q) {
        int c = c0 + q;
        float sv = __uint_as_float((dws[q] & 0xFFFFu) << 16);
        float sve = __uint_as_float(dws[q] & 0xFFFF0000u);
        trans[m][c][t] =
            sv * s_sc[2 * c] + sve * s_sc[2 * c + 1] + s_sh[2 * c] + s_sh[2 * c + 1];
      }
    }
    __syncthreads();
#pragma unroll
    for (int m = 0; m < 4; ++m) {
#pragma unroll
      for (int cc = 0; cc < 4; ++cc) {
        int c = cbase + 8 * cc;
        ob[(size_t)c * 32768 + (size_t)(i4 + m) * 1024 + t2] = trans[m][c][t2];
      }
    }
    __syncthreads();
  }
}

extern "C" void kernel_launch(void* const* d_in, const int* in_sizes, int n_in,
                              void* d_out, int out_size, void* d_ws, size_t ws_size,
                              hipStream_t stream) {
  const float* x        = (const float*)d_in[0];
  const float* qkv_w    = (const float*)d_in[1];
  const float* relative = (const float*)d_in[2];
  const float* gamma    = (const float*)d_in[3];
  const float* beta     = (const float*)d_in[4];
  float* out = (float*)d_out;

  __hip_bfloat16* qkv = (__hip_bfloat16*)d_ws;                              // 128 MB
  unsigned int* stk2 = (unsigned int*)((char*)d_ws + (size_t)134217728);    // 128 MB
  float* stats = (float*)((char*)d_ws + (size_t)268435456);                 // 4 KB
  // xThi/xTlo live in the stk2 region: written by K0b, read by K1, dead before
  // K2 writes stk2 (stream-ordered).
  unsigned short* xThi = (unsigned short*)stk2;           // 64 MB
  unsigned short* xTlo = xThi + 33554432;                 // 64 MB

  hipMemsetAsync(stats, 0, 1024 * sizeof(float), stream);
  k0_xsplit<<<dim3(2048), dim3(256), 0, stream>>>(x, xThi, xTlo);
  k1_mfma<<<dim3(4096), dim3(256), 0, stream>>>(qkv_w, xThi, xTlo, qkv);
  k2_attn_mfma<<<dim3(1024), dim3(256), 0, stream>>>(qkv, relative, stk2, stats);
  k3_finalize2<<<dim3(1024), dim3(256), 0, stream>>>(stk2, stats, gamma, beta, out);
}